// Round 2
// baseline (335.615 us; speedup 1.0000x reference)
//
#include <hip/hip_runtime.h>
#include <stddef.h>
#include <stdint.h>

#define B_   32
#define IN_  4096
#define OUT_ 14336

typedef short v8s __attribute__((ext_vector_type(8)));
typedef float v4f __attribute__((ext_vector_type(4)));

__device__ __constant__ float c_nf4[16] = {
    -1.0f, -0.6961928009986877f, -0.5250730514526367f, -0.39491748809814453f,
    -0.28444138169288635f, -0.18477343022823334f, -0.09105003625154495f, 0.0f,
    0.07958029955625534f, 0.16093020141124725f, 0.24611230194568634f,
    0.33791524171829224f, 0.44070982933044434f, 0.5626170039176941f,
    0.7229568362236023f, 1.0f};

__device__ __forceinline__ unsigned f2bf_u(float f) {
    union { float f; unsigned u; } v; v.f = f;
    return (v.u + 0x7FFFu + ((v.u >> 16) & 1u)) >> 16;   // RNE, no NaN inputs
}
__device__ __forceinline__ unsigned pack2(float lo, float hi) {
    return f2bf_u(lo) | (f2bf_u(hi) << 16);
}

// x[32][4096] f32 -> xB bf16 in B-fragment layout for mfma_f32_16x16x32_bf16.
// Fragment t = (kt*2 + bt)*64 + l holds B[k = kt*32 + (l>>4)*8 + j][n = bt*16 + (l&15)]
// at xB uint4-index t (8 bf16 per lane, j = vector element).
__global__ __launch_bounds__(256) void prep(const float* __restrict__ x,
                                            unsigned* __restrict__ xB) {
    int t  = blockIdx.x * 256 + threadIdx.x;   // 0..16383
    int kt = t >> 7;
    int bt = (t >> 6) & 1;
    int l  = t & 63;
    int b  = bt * 16 + (l & 15);
    int k0 = kt * 32 + (l >> 4) * 8;
    const float* xr = x + (size_t)b * IN_ + k0;
    float4 a = *(const float4*)xr;
    float4 c = *(const float4*)(xr + 4);
    uint4 w;
    w.x = pack2(a.x, a.y);
    w.y = pack2(a.z, a.w);
    w.z = pack2(c.x, c.y);
    w.w = pack2(c.z, c.w);
    *(uint4*)(xB + (size_t)t * 4) = w;
}

// out[b][o] = bias[o]  (pre-init so split-K blocks can pure-atomicAdd)
__global__ __launch_bounds__(256) void init_out(const float* __restrict__ bias,
                                                float* __restrict__ out) {
    int t   = blockIdx.x * 256 + threadIdx.x;   // 0..114687 (x4 floats)
    int o   = (t * 4) % OUT_;
    int row = (t * 4) / OUT_;
    float4 bv = *(const float4*)(bias + o);
    *(float4*)(out + (size_t)row * OUT_ + o) = bv;
}

// Grid (224, 4) x 256. Wave w of block (bx,kq): o-rows [bx*64 + w*16, +16),
// k in [kq*1024, +1024).  Dequant via 256-entry pair-LUT (unscaled bf16 pairs);
// per-64k-block absmax applied to the MFMA partial accumulator (D-row == A-row
// == output feature), folded into the main accumulator with 8 FMAs/block.
// Partials atomicAdd'ed into bias-pre-initialized out.
__global__ __launch_bounds__(256) void nf4_mfma(
    const int* __restrict__ codes, const float* __restrict__ absmax,
    const unsigned* __restrict__ xB, float* __restrict__ out) {
    __shared__ unsigned plut[256];
    plut[threadIdx.x] = pack2(c_nf4[threadIdx.x & 15], c_nf4[threadIdx.x >> 4]);
    __syncthreads();

    const int w  = threadIdx.x >> 6;
    const int l  = threadIdx.x & 63;
    const int o0 = blockIdx.x * 64 + w * 16;
    const int kq = blockIdx.y;                 // 0..3
    const int m  = l & 15;
    const int q  = l >> 4;

    const int kt0 = kq * 32;                   // k-step (32-k) index base
    const int*   crow = codes + (size_t)(o0 + m) * IN_ + q * 8 + (size_t)kt0 * 32;
    const uint4* xbp  = (const uint4*)xB + l + (size_t)kt0 * 128;
    const float* amp  = absmax + (size_t)(o0 + q * 4) * 64 + kq * 16;

    v4f main0 = {0.f, 0.f, 0.f, 0.f};
    v4f main1 = {0.f, 0.f, 0.f, 0.f};
    const v4f zro = {0.f, 0.f, 0.f, 0.f};

#pragma unroll 2
    for (int kb = 0; kb < 16; ++kb) {          // one 64-k absmax block per iter
        const int* cA = crow + (size_t)kb * 64;
        int4 c0 = *(const int4*)(cA);          // k-step A, codes 0..7
        int4 c1 = *(const int4*)(cA + 4);
        int4 c2 = *(const int4*)(cA + 32);     // k-step B
        int4 c3 = *(const int4*)(cA + 36);
        uint4 b0 = xbp[(size_t)kb * 256];        // step A, b-tile 0
        uint4 b1 = xbp[(size_t)kb * 256 + 64];   // step A, b-tile 1
        uint4 b2 = xbp[(size_t)kb * 256 + 128];  // step B, b-tile 0
        uint4 b3 = xbp[(size_t)kb * 256 + 192];  // step B, b-tile 1
        float am0 = amp[kb];
        float am1 = amp[kb + 64];
        float am2 = amp[kb + 128];
        float am3 = amp[kb + 192];

        union { uint4 u; v8s v; } aA, aB, f0, f1, f2, f3;
        aA.u.x = plut[c0.x | (c0.y << 4)];
        aA.u.y = plut[c0.z | (c0.w << 4)];
        aA.u.z = plut[c1.x | (c1.y << 4)];
        aA.u.w = plut[c1.z | (c1.w << 4)];
        aB.u.x = plut[c2.x | (c2.y << 4)];
        aB.u.y = plut[c2.z | (c2.w << 4)];
        aB.u.z = plut[c3.x | (c3.y << 4)];
        aB.u.w = plut[c3.z | (c3.w << 4)];
        f0.u = b0; f1.u = b1; f2.u = b2; f3.u = b3;

        v4f blk0 = __builtin_amdgcn_mfma_f32_16x16x32_bf16(aA.v, f0.v, zro, 0, 0, 0);
        v4f blk1 = __builtin_amdgcn_mfma_f32_16x16x32_bf16(aA.v, f1.v, zro, 0, 0, 0);
        blk0 = __builtin_amdgcn_mfma_f32_16x16x32_bf16(aB.v, f2.v, blk0, 0, 0, 0);
        blk1 = __builtin_amdgcn_mfma_f32_16x16x32_bf16(aB.v, f3.v, blk1, 0, 0, 0);

        main0[0] += am0 * blk0[0];  main1[0] += am0 * blk1[0];
        main0[1] += am1 * blk0[1];  main1[1] += am1 * blk1[1];
        main0[2] += am2 * blk0[2];  main1[2] += am2 * blk1[2];
        main0[3] += am3 * blk0[3];  main1[3] += am3 * blk1[3];
    }

    // D layout: col = l&15 (= batch b within tile), row = q*4 + r (= o offset)
    const int bc = l & 15;
    const int ob = o0 + q * 4;
#pragma unroll
    for (int r = 0; r < 4; ++r) {
        atomicAdd(&out[(size_t)bc * OUT_ + ob + r],        main0[r]);
        atomicAdd(&out[(size_t)(bc + 16) * OUT_ + ob + r], main1[r]);
    }
}

extern "C" void kernel_launch(void* const* d_in, const int* in_sizes, int n_in,
                              void* d_out, int out_size, void* d_ws, size_t ws_size,
                              hipStream_t stream) {
    const float* x      = (const float*)d_in[0];
    const int*   codes  = (const int*)d_in[1];
    const float* absmax = (const float*)d_in[2];
    const float* bias   = (const float*)d_in[3];
    float* out = (float*)d_out;
    unsigned* xB = (unsigned*)d_ws;   // 256 KB (ws known >= 512 KB)

    init_out<<<dim3(448), 256, 0, stream>>>(bias, out);
    prep<<<dim3(64), 256, 0, stream>>>(x, xB);
    nf4_mfma<<<dim3(OUT_ / 64, 4), 256, 0, stream>>>(codes, absmax, xB, out);
}